// Round 9
// baseline (1914.246 us; speedup 1.0000x reference)
//
#include <hip/hip_runtime.h>
#include <hip/hip_bf16.h>
#include <stdint.h>

#define M_ROWS 8192
#define K_DIM  1024
#define N_COLS 4096
#define N_CLUS 64

// fragment-native layout (16B groups of 8 bf16):
// A: [bm(32)][kt(16)][kk(2)][mi(8)][wm(2)][l(64)]   -> 32768 groups / bm
//    (per-(bm,kt) region = 2048 groups = 32 KB CONTIGUOUS -> LDS memcpy)
// B: [bn(16)][kt(16)][kk(2)][ni(4)][wn(4)][l(64)]   -> 32768 groups / bn
// group (.,l) holds src[row][k0..k0+8): row = base + frag*16 + (l&15),
// k0 = kt*64 + (kk*4 + (l>>4))*8.
#define A_GROUPS (32u * 32768u)   // 1048576
#define B_GROUPS (16u * 32768u)   // 524288
#define C_GROUPS (64u * 128u)     // 8192

typedef short bf16x8 __attribute__((ext_vector_type(8)));
typedef float f32x4  __attribute__((ext_vector_type(4)));

__device__ __forceinline__ unsigned short f2bf(float f) {
  unsigned int u = __float_as_uint(f);
  unsigned int r = (u + 0x7FFFu + ((u >> 16) & 1u)) >> 16;
  return (unsigned short)r;
}

// ---------------- fp32 -> bf16 native-layout conversion + mask init ----------------
__global__ __launch_bounds__(256) void convert_kernel(
    const float* __restrict__ x, const float* __restrict__ wgt,
    const float* __restrict__ cent,
    unsigned short* __restrict__ an, unsigned short* __restrict__ bnat,
    unsigned short* __restrict__ cb,
    unsigned long long* __restrict__ mask) {
  const unsigned g = blockIdx.x * 256 + threadIdx.x;
  if (g == 0) *mask = 0ull;
  const float* src; unsigned short* dst; unsigned row, k0;
  if (g < A_GROUPS) {
    const unsigned o = g;
    const unsigned l = o & 63, wm = (o >> 6) & 1, mi = (o >> 7) & 7,
                   kk = (o >> 10) & 1, kt = (o >> 11) & 15, bm = o >> 15;
    row = bm * 256 + wm * 128 + mi * 16 + (l & 15);
    k0  = kt * 64 + (kk * 4 + (l >> 4)) * 8;
    src = x; dst = an + (size_t)o * 8;
  } else if (g < A_GROUPS + B_GROUPS) {
    const unsigned o = g - A_GROUPS;
    const unsigned l = o & 63, wn = (o >> 6) & 3, ni = (o >> 8) & 3,
                   kk = (o >> 10) & 1, kt = (o >> 11) & 15, bn = o >> 15;
    row = bn * 256 + wn * 64 + ni * 16 + (l & 15);
    k0  = kt * 64 + (kk * 4 + (l >> 4)) * 8;
    src = wgt; dst = bnat + (size_t)o * 8;
  } else {
    const unsigned o = g - A_GROUPS - B_GROUPS;
    row = o >> 7; k0 = (o & 127) * 8;
    src = cent; dst = cb + (size_t)o * 8;
  }
  const float4 v0 = *(const float4*)&src[(size_t)row * K_DIM + k0];
  const float4 v1 = *(const float4*)&src[(size_t)row * K_DIM + k0 + 4];
  union { unsigned short u[8]; uint4 q; } o16;
  o16.u[0] = f2bf(v0.x); o16.u[1] = f2bf(v0.y); o16.u[2] = f2bf(v0.z); o16.u[3] = f2bf(v0.w);
  o16.u[4] = f2bf(v1.x); o16.u[5] = f2bf(v1.y); o16.u[6] = f2bf(v1.z); o16.u[7] = f2bf(v1.w);
  *(uint4*)dst = o16.q;
}

// ---------------- routing (reads native A layout): cluster-active mask ----------------
// 256 blocks x 1 wave; block = (bm, wm, mp) -> rows bm*256+wm*128+mp*32 .. +32.
__global__ __launch_bounds__(64) void routing_mfma_kernel(
    const unsigned short* __restrict__ an, const unsigned short* __restrict__ cb,
    unsigned long long* __restrict__ mask) {
  __shared__ unsigned short Xl[2048];   // 4 KB: groups [kk][dm][l]
  __shared__ unsigned short Cl[4096];   // 8 KB: groups [kk][crow][chi]
  const int t = threadIdx.x;
  const int lr = t & 15;
  const int hi4 = t >> 4;
  const int bm = blockIdx.x >> 3, wm = (blockIdx.x >> 2) & 1, mp = blockIdx.x & 3;
  const size_t abase = (size_t)bm * 32768 + wm * 64;   // group units

  f32x4 acc[2][4];
  #pragma unroll
  for (int i = 0; i < 2; ++i)
    #pragma unroll
    for (int j = 0; j < 4; ++j) acc[i][j] = {0.f, 0.f, 0.f, 0.f};

  for (int kt = 0; kt < 16; ++kt) {
    #pragma unroll
    for (int kk2 = 0; kk2 < 2; ++kk2)
      #pragma unroll
      for (int dm = 0; dm < 2; ++dm) {
        const size_t grp = abase + kt * 2048 + kk2 * 1024 + (mp * 2 + dm) * 128;
        const unsigned short* gx = an + (grp + t) * 8;   // per-lane source
        char* dx = (char*)Xl + (kk2 * 128 + dm * 64) * 16;
        __builtin_amdgcn_global_load_lds((const __attribute__((address_space(1))) void*)gx,
                                         (__attribute__((address_space(3))) void*)dx, 16, 0, 0);
      }
    #pragma unroll
    for (int r = 0; r < 8; ++r) {
      const int flat = r * 64 + t;
      const int ckk = flat >> 8, crow = (flat >> 2) & 63, chi = flat & 3;
      const unsigned short* gc = cb + (size_t)crow * K_DIM + kt * 64 + ckk * 32 + chi * 8;
      char* dc = (char*)Cl + r * 1024;
      __builtin_amdgcn_global_load_lds((const __attribute__((address_space(1))) void*)gc,
                                       (__attribute__((address_space(3))) void*)dc, 16, 0, 0);
    }
    __syncthreads();

    #pragma unroll
    for (int kk = 0; kk < 2; ++kk) {
      bf16x8 af[2], cf[4];
      #pragma unroll
      for (int dm = 0; dm < 2; ++dm)
        af[dm] = *(const bf16x8*)&Xl[kk * 1024 + dm * 512 + t * 8];
      #pragma unroll
      for (int ni = 0; ni < 4; ++ni)
        cf[ni] = *(const bf16x8*)&Cl[kk * 2048 + (ni * 16 + lr) * 32 + hi4 * 8];
      #pragma unroll
      for (int dm = 0; dm < 2; ++dm)
        #pragma unroll
        for (int ni = 0; ni < 4; ++ni)
          acc[dm][ni] = __builtin_amdgcn_mfma_f32_16x16x32_bf16(af[dm], cf[ni], acc[dm][ni], 0, 0, 0);
    }
    __syncthreads();
  }

  bool colflag[4] = {false, false, false, false};
  #pragma unroll
  for (int dm = 0; dm < 2; ++dm) {
    #pragma unroll
    for (int j = 0; j < 4; ++j) {
      const float v0 = acc[dm][0][j], v1 = acc[dm][1][j],
                  v2 = acc[dm][2][j], v3 = acc[dm][3][j];
      float m = fmaxf(fmaxf(v0, v1), fmaxf(v2, v3));
      #pragma unroll
      for (int off = 8; off >= 1; off >>= 1) m = fmaxf(m, __shfl_xor(m, off));
      float S = expf(v0 - m) + expf(v1 - m) + expf(v2 - m) + expf(v3 - m);
      #pragma unroll
      for (int off = 8; off >= 1; off >>= 1) S += __shfl_xor(S, off);
      const float thr = logf(1e-4f * S);
      colflag[0] |= (v0 - m) > thr;
      colflag[1] |= (v1 - m) > thr;
      colflag[2] |= (v2 - m) > thr;
      colflag[3] |= (v3 - m) > thr;
    }
  }
  unsigned long long bits = 0;
  #pragma unroll
  for (int ni = 0; ni < 4; ++ni) {
    unsigned long long u = __ballot(colflag[ni]);
    u |= u >> 32; u |= u >> 16;
    bits |= (u & 0xFFFFull) << (ni * 16);
  }
  if (t == 0) atomicOr(mask, bits);
}

// ---------------- hybrid bf16 MFMA GEMM: A via LDS (1x), B direct (2x) ----------------
// Block 256x256, 8 waves (2 wm x 4 wn), wave tile 128x64, acc[8][4] (128 AGPR).
// A per-(bm,kt) region is 32KB contiguous -> linear gload_lds, conflict-free
// contiguous ds_reads. One barrier per K-tile; counted vmcnt(4) keeps next
// B prefetch in flight.
__global__ __launch_bounds__(512, 4) void gemm_kernel(
    const unsigned short* __restrict__ an, const unsigned short* __restrict__ bnat,
    const float* __restrict__ bias, const int* __restrict__ assign,
    const unsigned long long* __restrict__ maskp,
    float* __restrict__ out) {
  __shared__ unsigned short Al[2][16384];   // 2 x 32 KB

  const int t = threadIdx.x;
  const int l = t & 63;
  const int w = t >> 6;          // 0..7
  const int wm = w & 1;
  const int wn = w >> 1;         // 0..3
  const int lr = l & 15;
  const int hi4 = l >> 4;

  const int bid = blockIdx.x;
  const int swz = (bid & 7) * (gridDim.x >> 3) + (bid >> 3);   // 512 % 8 == 0
  const int bm = swz >> 4, bn = swz & 15;                      // 32 x 16 tiles
  const int m0 = bm * 256, n0 = bn * 256;

  const unsigned short* pB = bnat + ((size_t)bn * 32768 + wn * 64 + l) * 8;
  const size_t aBase = (size_t)bm * 32768;   // group units

  f32x4 acc[8][4];
  #pragma unroll
  for (int i = 0; i < 8; ++i)
    #pragma unroll
    for (int j = 0; j < 4; ++j) acc[i][j] = {0.f, 0.f, 0.f, 0.f};

  bf16x8 Af[2][8];   // [kk][mi]
  bf16x8 Bf[2][4];   // [slot][ni]

#define ASTAGE(BUF, KT) do {                                                   \
    _Pragma("unroll")                                                          \
    for (int _r = 0; _r < 4; ++_r) {                                           \
      const unsigned short* _g = an + (aBase + (KT) * 2048 + _r * 512 + t) * 8;\
      char* _d = (char*)&Al[BUF][0] + (_r * 512 + w * 64) * 16;                \
      __builtin_amdgcn_global_load_lds(                                        \
          (const __attribute__((address_space(1))) void*)_g,                   \
          (__attribute__((address_space(3))) void*)_d, 16, 0, 0);              \
    }                                                                          \
  } while (0)

#define LDAF(BUF) do {                                                         \
    _Pragma("unroll")                                                          \
    for (int _kk = 0; _kk < 2; ++_kk)                                          \
      _Pragma("unroll")                                                        \
      for (int _mi = 0; _mi < 8; ++_mi)                                        \
        Af[_kk][_mi] = *(const bf16x8*)&Al[BUF][(size_t)(_kk * 1024 + _mi * 128 + wm * 64 + l) * 8]; \
  } while (0)

#define LDBF(SLOT, KT, KK) do {                                                \
    _Pragma("unroll")                                                          \
    for (int _ni = 0; _ni < 4; ++_ni)                                          \
      Bf[SLOT][_ni] = *(const bf16x8*)(pB + ((size_t)(KT) * 2048 + (KK) * 1024 + _ni * 256) * 8); \
  } while (0)

#define MFMAS(KK, SLOT) do {                                                   \
    __builtin_amdgcn_s_setprio(1);                                             \
    _Pragma("unroll")                                                          \
    for (int _mi = 0; _mi < 8; ++_mi)                                          \
      _Pragma("unroll")                                                        \
      for (int _ni = 0; _ni < 4; ++_ni)                                        \
        acc[_mi][_ni] = __builtin_amdgcn_mfma_f32_16x16x32_bf16(               \
            Af[KK][_mi], Bf[SLOT][_ni], acc[_mi][_ni], 0, 0, 0);               \
    __builtin_amdgcn_s_setprio(0);                                             \
  } while (0)

#define WAITV(N) asm volatile("s_waitcnt vmcnt(" #N ")" ::: "memory")
#define BAR() do { asm volatile("" ::: "memory"); __builtin_amdgcn_s_barrier(); } while (0)

  // ---- prologue: stage A(0), prefetch B(0,kk0) ----
  ASTAGE(0, 0);
  LDBF(0, 0, 0);
  WAITV(4);            // A-stage drained; B(0,0) may stay in flight
  BAR();

  // ---- main loop: kt = 0..14 ----
  for (int kt = 0; kt < 15; ++kt) {
    const int c = kt & 1;
    if (c == 0) {
      ASTAGE(1, kt + 1);
      LDAF(0);
      LDBF(1, kt, 1);
      MFMAS(0, 0);
      LDBF(0, kt + 1, 0);
      MFMAS(1, 1);
    } else {
      ASTAGE(0, kt + 1);
      LDAF(1);
      LDBF(1, kt, 1);
      MFMAS(0, 0);
      LDBF(0, kt + 1, 0);
      MFMAS(1, 1);
    }
    WAITV(4);          // drain A-stage(kt+1); next-B prefetch stays in flight
    BAR();
  }

  // ---- tail: kt = 15 (buffer 1) ----
  LDAF(1);
  LDBF(1, 15, 1);
  MFMAS(0, 0);
  MFMAS(1, 1);

  // ---- epilogue: fused mask + bias ----
  const unsigned long long mask = *maskp;
  #pragma unroll
  for (int ni = 0; ni < 4; ++ni) {
    const int col = n0 + wn * 64 + ni * 16 + lr;
    const int a = assign[col];
    const bool act = (mask >> a) & 1ull;
    const float bv = bias[col];
    #pragma unroll
    for (int mi = 0; mi < 8; ++mi) {
      const int rowb = m0 + wm * 128 + mi * 16 + hi4 * 4;
      #pragma unroll
      for (int j = 0; j < 4; ++j) {
        out[(size_t)(rowb + j) * N_COLS + col] = act ? (acc[mi][ni][j] + bv) : 0.0f;
      }
    }
  }
#undef ASTAGE
#undef LDAF
#undef LDBF
#undef MFMAS
#undef WAITV
#undef BAR
}

extern "C" void kernel_launch(void* const* d_in, const int* in_sizes, int n_in,
                              void* d_out, int out_size, void* d_ws, size_t ws_size,
                              hipStream_t stream) {
  const float* x    = (const float*)d_in[0];
  const float* wgt  = (const float*)d_in[1];
  const float* bias = (const float*)d_in[2];
  const float* cent = (const float*)d_in[3];
  const int* assign = (const int*)d_in[4];
  float* out = (float*)d_out;

  unsigned long long* mask = (unsigned long long*)d_ws;
  unsigned short* an   = (unsigned short*)((char*)d_ws + 256);
  unsigned short* bnat = an + (size_t)A_GROUPS * 8;    // +16 MB
  unsigned short* cb   = bnat + (size_t)B_GROUPS * 8;  // +8 MB (cb: 128 KB)

  const unsigned total_groups = A_GROUPS + B_GROUPS + C_GROUPS;
  hipLaunchKernelGGL(convert_kernel, dim3(total_groups / 256), dim3(256), 0, stream,
                     x, wgt, cent, an, bnat, cb, mask);
  hipLaunchKernelGGL(routing_mfma_kernel, dim3(256), dim3(64), 0, stream,
                     an, cb, mask);
  hipLaunchKernelGGL(gemm_kernel, dim3((M_ROWS / 256) * (N_COLS / 256)), dim3(512), 0, stream,
                     an, bnat, bias, assign, mask, out);
}

// Round 10
// 592.004 us; speedup vs baseline: 3.2335x; 3.2335x over previous
//
#include <hip/hip_runtime.h>
#include <hip/hip_bf16.h>
#include <stdint.h>

#define M_ROWS 8192
#define K_DIM  1024
#define N_COLS 4096
#define N_CLUS 64

// fragment-native layout (16B groups of 8 bf16):
// A: [bm(32)][kt(16)][kk(2)][mi(8)][wm(2)][l(64)]   -> 32768 groups / bm
//    (per-(bm,kt) region = 2048 groups = 32 KB CONTIGUOUS -> LDS memcpy)
// B: [bn(16)][kt(16)][kk(2)][ni(4)][wn(4)][l(64)]   -> 32768 groups / bn
// group (.,l) holds src[row][k0..k0+8): row = base + frag*16 + (l&15),
// k0 = kt*64 + (kk*4 + (l>>4))*8.
#define A_GROUPS (32u * 32768u)   // 1048576
#define B_GROUPS (16u * 32768u)   // 524288
#define C_GROUPS (64u * 128u)     // 8192

typedef short bf16x8 __attribute__((ext_vector_type(8)));
typedef float f32x4  __attribute__((ext_vector_type(4)));

__device__ __forceinline__ unsigned short f2bf(float f) {
  unsigned int u = __float_as_uint(f);
  unsigned int r = (u + 0x7FFFu + ((u >> 16) & 1u)) >> 16;
  return (unsigned short)r;
}

// ---------------- fp32 -> bf16 native-layout conversion + mask init ----------------
__global__ __launch_bounds__(256) void convert_kernel(
    const float* __restrict__ x, const float* __restrict__ wgt,
    const float* __restrict__ cent,
    unsigned short* __restrict__ an, unsigned short* __restrict__ bnat,
    unsigned short* __restrict__ cb,
    unsigned long long* __restrict__ mask) {
  const unsigned g = blockIdx.x * 256 + threadIdx.x;
  if (g == 0) *mask = 0ull;
  const float* src; unsigned short* dst; unsigned row, k0;
  if (g < A_GROUPS) {
    const unsigned o = g;
    const unsigned l = o & 63, wm = (o >> 6) & 1, mi = (o >> 7) & 7,
                   kk = (o >> 10) & 1, kt = (o >> 11) & 15, bm = o >> 15;
    row = bm * 256 + wm * 128 + mi * 16 + (l & 15);
    k0  = kt * 64 + (kk * 4 + (l >> 4)) * 8;
    src = x; dst = an + (size_t)o * 8;
  } else if (g < A_GROUPS + B_GROUPS) {
    const unsigned o = g - A_GROUPS;
    const unsigned l = o & 63, wn = (o >> 6) & 3, ni = (o >> 8) & 3,
                   kk = (o >> 10) & 1, kt = (o >> 11) & 15, bn = o >> 15;
    row = bn * 256 + wn * 64 + ni * 16 + (l & 15);
    k0  = kt * 64 + (kk * 4 + (l >> 4)) * 8;
    src = wgt; dst = bnat + (size_t)o * 8;
  } else {
    const unsigned o = g - A_GROUPS - B_GROUPS;
    row = o >> 7; k0 = (o & 127) * 8;
    src = cent; dst = cb + (size_t)o * 8;
  }
  const float4 v0 = *(const float4*)&src[(size_t)row * K_DIM + k0];
  const float4 v1 = *(const float4*)&src[(size_t)row * K_DIM + k0 + 4];
  union { unsigned short u[8]; uint4 q; } o16;
  o16.u[0] = f2bf(v0.x); o16.u[1] = f2bf(v0.y); o16.u[2] = f2bf(v0.z); o16.u[3] = f2bf(v0.w);
  o16.u[4] = f2bf(v1.x); o16.u[5] = f2bf(v1.y); o16.u[6] = f2bf(v1.z); o16.u[7] = f2bf(v1.w);
  *(uint4*)dst = o16.q;
}

// ---------------- routing (reads native A layout): cluster-active mask ----------------
// 256 blocks x 1 wave; block = (bm, wm, mp) -> rows bm*256+wm*128+mp*32 .. +32.
__global__ __launch_bounds__(64) void routing_mfma_kernel(
    const unsigned short* __restrict__ an, const unsigned short* __restrict__ cb,
    unsigned long long* __restrict__ mask) {
  __shared__ unsigned short Xl[2048];   // 4 KB: groups [kk][dm][l]
  __shared__ unsigned short Cl[4096];   // 8 KB: groups [kk][crow][chi]
  const int t = threadIdx.x;
  const int lr = t & 15;
  const int hi4 = t >> 4;
  const int bm = blockIdx.x >> 3, wm = (blockIdx.x >> 2) & 1, mp = blockIdx.x & 3;
  const size_t abase = (size_t)bm * 32768 + wm * 64;   // group units

  f32x4 acc[2][4];
  #pragma unroll
  for (int i = 0; i < 2; ++i)
    #pragma unroll
    for (int j = 0; j < 4; ++j) acc[i][j] = {0.f, 0.f, 0.f, 0.f};

  for (int kt = 0; kt < 16; ++kt) {
    #pragma unroll
    for (int kk2 = 0; kk2 < 2; ++kk2)
      #pragma unroll
      for (int dm = 0; dm < 2; ++dm) {
        const size_t grp = abase + kt * 2048 + kk2 * 1024 + (mp * 2 + dm) * 128;
        const unsigned short* gx = an + (grp + t) * 8;   // per-lane source
        char* dx = (char*)Xl + (kk2 * 128 + dm * 64) * 16;
        __builtin_amdgcn_global_load_lds((const __attribute__((address_space(1))) void*)gx,
                                         (__attribute__((address_space(3))) void*)dx, 16, 0, 0);
      }
    #pragma unroll
    for (int r = 0; r < 8; ++r) {
      const int flat = r * 64 + t;
      const int ckk = flat >> 8, crow = (flat >> 2) & 63, chi = flat & 3;
      const unsigned short* gc = cb + (size_t)crow * K_DIM + kt * 64 + ckk * 32 + chi * 8;
      char* dc = (char*)Cl + r * 1024;
      __builtin_amdgcn_global_load_lds((const __attribute__((address_space(1))) void*)gc,
                                       (__attribute__((address_space(3))) void*)dc, 16, 0, 0);
    }
    __syncthreads();

    #pragma unroll
    for (int kk = 0; kk < 2; ++kk) {
      bf16x8 af[2], cf[4];
      #pragma unroll
      for (int dm = 0; dm < 2; ++dm)
        af[dm] = *(const bf16x8*)&Xl[kk * 1024 + dm * 512 + t * 8];
      #pragma unroll
      for (int ni = 0; ni < 4; ++ni)
        cf[ni] = *(const bf16x8*)&Cl[kk * 2048 + (ni * 16 + lr) * 32 + hi4 * 8];
      #pragma unroll
      for (int dm = 0; dm < 2; ++dm)
        #pragma unroll
        for (int ni = 0; ni < 4; ++ni)
          acc[dm][ni] = __builtin_amdgcn_mfma_f32_16x16x32_bf16(af[dm], cf[ni], acc[dm][ni], 0, 0, 0);
    }
    __syncthreads();
  }

  bool colflag[4] = {false, false, false, false};
  #pragma unroll
  for (int dm = 0; dm < 2; ++dm) {
    #pragma unroll
    for (int j = 0; j < 4; ++j) {
      const float v0 = acc[dm][0][j], v1 = acc[dm][1][j],
                  v2 = acc[dm][2][j], v3 = acc[dm][3][j];
      float m = fmaxf(fmaxf(v0, v1), fmaxf(v2, v3));
      #pragma unroll
      for (int off = 8; off >= 1; off >>= 1) m = fmaxf(m, __shfl_xor(m, off));
      float S = expf(v0 - m) + expf(v1 - m) + expf(v2 - m) + expf(v3 - m);
      #pragma unroll
      for (int off = 8; off >= 1; off >>= 1) S += __shfl_xor(S, off);
      const float thr = logf(1e-4f * S);
      colflag[0] |= (v0 - m) > thr;
      colflag[1] |= (v1 - m) > thr;
      colflag[2] |= (v2 - m) > thr;
      colflag[3] |= (v3 - m) > thr;
    }
  }
  unsigned long long bits = 0;
  #pragma unroll
  for (int ni = 0; ni < 4; ++ni) {
    unsigned long long u = __ballot(colflag[ni]);
    u |= u >> 32; u |= u >> 16;
    bits |= (u & 0xFFFFull) << (ni * 16);
  }
  if (t == 0) atomicOr(mask, bits);
}

// ---------------- hybrid bf16 MFMA GEMM: A via LDS (1x), B direct (2x) ----------------
// Block 256x256, 8 waves (2 wm x 4 wn), wave tile 128x64, acc[8][4] (128 AGPR).
// __launch_bounds__(512, 2): 256-reg cap — the R9 failure was (512,4)'s
// 128-reg cap spilling the ~250-reg footprint to scratch.
__global__ __launch_bounds__(512, 2) void gemm_kernel(
    const unsigned short* __restrict__ an, const unsigned short* __restrict__ bnat,
    const float* __restrict__ bias, const int* __restrict__ assign,
    const unsigned long long* __restrict__ maskp,
    float* __restrict__ out) {
  __shared__ unsigned short Al[2][16384];   // 2 x 32 KB

  const int t = threadIdx.x;
  const int l = t & 63;
  const int w = t >> 6;          // 0..7
  const int wm = w & 1;
  const int wn = w >> 1;         // 0..3
  const int lr = l & 15;
  const int hi4 = l >> 4;

  const int bid = blockIdx.x;
  const int swz = (bid & 7) * (gridDim.x >> 3) + (bid >> 3);   // 512 % 8 == 0
  const int bm = swz >> 4, bn = swz & 15;                      // 32 x 16 tiles
  const int m0 = bm * 256, n0 = bn * 256;

  const unsigned short* pB = bnat + ((size_t)bn * 32768 + wn * 64 + l) * 8;
  const size_t aBase = (size_t)bm * 32768;   // group units

  f32x4 acc[8][4];
  #pragma unroll
  for (int i = 0; i < 8; ++i)
    #pragma unroll
    for (int j = 0; j < 4; ++j) acc[i][j] = {0.f, 0.f, 0.f, 0.f};

  bf16x8 Af[2][8];   // [kk][mi]
  bf16x8 Bf[2][4];   // [slot][ni]

#define ASTAGE(BUF, KT) do {                                                   \
    _Pragma("unroll")                                                          \
    for (int _r = 0; _r < 4; ++_r) {                                           \
      const unsigned short* _g = an + (aBase + (KT) * 2048 + _r * 512 + t) * 8;\
      char* _d = (char*)&Al[BUF][0] + (_r * 512 + w * 64) * 16;                \
      __builtin_amdgcn_global_load_lds(                                        \
          (const __attribute__((address_space(1))) void*)_g,                   \
          (__attribute__((address_space(3))) void*)_d, 16, 0, 0);              \
    }                                                                          \
  } while (0)

#define LDAF(BUF) do {                                                         \
    _Pragma("unroll")                                                          \
    for (int _kk = 0; _kk < 2; ++_kk)                                          \
      _Pragma("unroll")                                                        \
      for (int _mi = 0; _mi < 8; ++_mi)                                        \
        Af[_kk][_mi] = *(const bf16x8*)&Al[BUF][(size_t)(_kk * 1024 + _mi * 128 + wm * 64 + l) * 8]; \
  } while (0)

#define LDBF(SLOT, KT, KK) do {                                                \
    _Pragma("unroll")                                                          \
    for (int _ni = 0; _ni < 4; ++_ni)                                          \
      Bf[SLOT][_ni] = *(const bf16x8*)(pB + ((size_t)(KT) * 2048 + (KK) * 1024 + _ni * 256) * 8); \
  } while (0)

#define MFMAS(KK, SLOT) do {                                                   \
    __builtin_amdgcn_s_setprio(1);                                             \
    _Pragma("unroll")                                                          \
    for (int _mi = 0; _mi < 8; ++_mi)                                          \
      _Pragma("unroll")                                                        \
      for (int _ni = 0; _ni < 4; ++_ni)                                        \
        acc[_mi][_ni] = __builtin_amdgcn_mfma_f32_16x16x32_bf16(               \
            Af[KK][_mi], Bf[SLOT][_ni], acc[_mi][_ni], 0, 0, 0);               \
    __builtin_amdgcn_s_setprio(0);                                             \
  } while (0)

#define WAITV(N) asm volatile("s_waitcnt vmcnt(" #N ")" ::: "memory")
#define BAR() do { asm volatile("" ::: "memory"); __builtin_amdgcn_s_barrier(); } while (0)

  // ---- prologue: stage A(0), prefetch B(0,kk0) ----
  ASTAGE(0, 0);
  LDBF(0, 0, 0);
  WAITV(4);            // A-stage drained; B(0,0) may stay in flight
  BAR();

  // ---- main loop: kt = 0..14 ----
  for (int kt = 0; kt < 15; ++kt) {
    const int c = kt & 1;
    if (c == 0) {
      ASTAGE(1, kt + 1);
      LDAF(0);
      LDBF(1, kt, 1);
      MFMAS(0, 0);
      LDBF(0, kt + 1, 0);
      MFMAS(1, 1);
    } else {
      ASTAGE(0, kt + 1);
      LDAF(1);
      LDBF(1, kt, 1);
      MFMAS(0, 0);
      LDBF(0, kt + 1, 0);
      MFMAS(1, 1);
    }
    WAITV(4);          // drain A-stage(kt+1); next-B prefetch stays in flight
    BAR();
  }

  // ---- tail: kt = 15 (buffer 1) ----
  LDAF(1);
  LDBF(1, 15, 1);
  MFMAS(0, 0);
  MFMAS(1, 1);

  // ---- epilogue: fused mask + bias ----
  const unsigned long long mask = *maskp;
  #pragma unroll
  for (int ni = 0; ni < 4; ++ni) {
    const int col = n0 + wn * 64 + ni * 16 + lr;
    const int a = assign[col];
    const bool act = (mask >> a) & 1ull;
    const float bv = bias[col];
    #pragma unroll
    for (int mi = 0; mi < 8; ++mi) {
      const int rowb = m0 + wm * 128 + mi * 16 + hi4 * 4;
      #pragma unroll
      for (int j = 0; j < 4; ++j) {
        out[(size_t)(rowb + j) * N_COLS + col] = act ? (acc[mi][ni][j] + bv) : 0.0f;
      }
    }
  }
#undef ASTAGE
#undef LDAF
#undef LDBF
#undef MFMAS
#undef WAITV
#undef BAR
}

extern "C" void kernel_launch(void* const* d_in, const int* in_sizes, int n_in,
                              void* d_out, int out_size, void* d_ws, size_t ws_size,
                              hipStream_t stream) {
  const float* x    = (const float*)d_in[0];
  const float* wgt  = (const float*)d_in[1];
  const float* bias = (const float*)d_in[2];
  const float* cent = (const float*)d_in[3];
  const int* assign = (const int*)d_in[4];
  float* out = (float*)d_out;

  unsigned long long* mask = (unsigned long long*)d_ws;
  unsigned short* an   = (unsigned short*)((char*)d_ws + 256);
  unsigned short* bnat = an + (size_t)A_GROUPS * 8;    // +16 MB
  unsigned short* cb   = bnat + (size_t)B_GROUPS * 8;  // +8 MB (cb: 128 KB)

  const unsigned total_groups = A_GROUPS + B_GROUPS + C_GROUPS;
  hipLaunchKernelGGL(convert_kernel, dim3(total_groups / 256), dim3(256), 0, stream,
                     x, wgt, cent, an, bnat, cb, mask);
  hipLaunchKernelGGL(routing_mfma_kernel, dim3(256), dim3(64), 0, stream,
                     an, cb, mask);
  hipLaunchKernelGGL(gemm_kernel, dim3((M_ROWS / 256) * (N_COLS / 256)), dim3(512), 0, stream,
                     an, bnat, bias, assign, mask, out);
}

// Round 11
// 109.547 us; speedup vs baseline: 17.4742x; 5.4041x over previous
//
#include <hip/hip_runtime.h>
#include <hip/hip_bf16.h>
#include <stdint.h>

#define M_ROWS 8192
#define K_DIM  1024
#define N_COLS 4096
#define N_CLUS 64

// fragment-native layout (16B groups of 8 bf16):
// A: [bm(32)][kt(16)][kk(2)][mi(8)][wm(2)][l(64)]   -> 32768 groups / bm
//    (per-(bm,kt) region = 2048 groups = 32 KB CONTIGUOUS -> LDS memcpy)
// B: [bn(16)][kt(16)][kk(2)][ni(4)][wn(4)][l(64)]   -> 32768 groups / bn
// group (.,l) holds src[row][k0..k0+8): row = base + frag*16 + (l&15),
// k0 = kt*64 + (kk*4 + (l>>4))*8.
#define A_GROUPS (32u * 32768u)   // 1048576
#define B_GROUPS (16u * 32768u)   // 524288
#define C_GROUPS (64u * 128u)     // 8192

typedef short bf16x8 __attribute__((ext_vector_type(8)));
typedef float f32x4  __attribute__((ext_vector_type(4)));

__device__ __forceinline__ unsigned short f2bf(float f) {
  unsigned int u = __float_as_uint(f);
  unsigned int r = (u + 0x7FFFu + ((u >> 16) & 1u)) >> 16;
  return (unsigned short)r;
}

// ---------------- fp32 -> bf16 native-layout conversion + mask init ----------------
__global__ __launch_bounds__(256) void convert_kernel(
    const float* __restrict__ x, const float* __restrict__ wgt,
    const float* __restrict__ cent,
    unsigned short* __restrict__ an, unsigned short* __restrict__ bnat,
    unsigned short* __restrict__ cb,
    unsigned long long* __restrict__ mask) {
  const unsigned g = blockIdx.x * 256 + threadIdx.x;
  if (g == 0) *mask = 0ull;
  const float* src; unsigned short* dst; unsigned row, k0;
  if (g < A_GROUPS) {
    const unsigned o = g;
    const unsigned l = o & 63, wm = (o >> 6) & 1, mi = (o >> 7) & 7,
                   kk = (o >> 10) & 1, kt = (o >> 11) & 15, bm = o >> 15;
    row = bm * 256 + wm * 128 + mi * 16 + (l & 15);
    k0  = kt * 64 + (kk * 4 + (l >> 4)) * 8;
    src = x; dst = an + (size_t)o * 8;
  } else if (g < A_GROUPS + B_GROUPS) {
    const unsigned o = g - A_GROUPS;
    const unsigned l = o & 63, wn = (o >> 6) & 3, ni = (o >> 8) & 3,
                   kk = (o >> 10) & 1, kt = (o >> 11) & 15, bn = o >> 15;
    row = bn * 256 + wn * 64 + ni * 16 + (l & 15);
    k0  = kt * 64 + (kk * 4 + (l >> 4)) * 8;
    src = wgt; dst = bnat + (size_t)o * 8;
  } else {
    const unsigned o = g - A_GROUPS - B_GROUPS;
    row = o >> 7; k0 = (o & 127) * 8;
    src = cent; dst = cb + (size_t)o * 8;
  }
  const float4 v0 = *(const float4*)&src[(size_t)row * K_DIM + k0];
  const float4 v1 = *(const float4*)&src[(size_t)row * K_DIM + k0 + 4];
  union { unsigned short u[8]; uint4 q; } o16;
  o16.u[0] = f2bf(v0.x); o16.u[1] = f2bf(v0.y); o16.u[2] = f2bf(v0.z); o16.u[3] = f2bf(v0.w);
  o16.u[4] = f2bf(v1.x); o16.u[5] = f2bf(v1.y); o16.u[6] = f2bf(v1.z); o16.u[7] = f2bf(v1.w);
  *(uint4*)dst = o16.q;
}

// ---------------- routing (reads native A layout): cluster-active mask ----------------
// 256 blocks x 1 wave; block = (bm, wm, mp) -> rows bm*256+wm*128+mp*32 .. +32.
__global__ __launch_bounds__(64) void routing_mfma_kernel(
    const unsigned short* __restrict__ an, const unsigned short* __restrict__ cb,
    unsigned long long* __restrict__ mask) {
  __shared__ unsigned short Xl[2048];   // 4 KB: groups [kk][dm][l]
  __shared__ unsigned short Cl[4096];   // 8 KB: groups [kk][crow][chi]
  const int t = threadIdx.x;
  const int lr = t & 15;
  const int hi4 = t >> 4;
  const int bm = blockIdx.x >> 3, wm = (blockIdx.x >> 2) & 1, mp = blockIdx.x & 3;
  const size_t abase = (size_t)bm * 32768 + wm * 64;   // group units

  f32x4 acc[2][4];
  #pragma unroll
  for (int i = 0; i < 2; ++i)
    #pragma unroll
    for (int j = 0; j < 4; ++j) acc[i][j] = {0.f, 0.f, 0.f, 0.f};

  for (int kt = 0; kt < 16; ++kt) {
    #pragma unroll
    for (int kk2 = 0; kk2 < 2; ++kk2)
      #pragma unroll
      for (int dm = 0; dm < 2; ++dm) {
        const size_t grp = abase + kt * 2048 + kk2 * 1024 + (mp * 2 + dm) * 128;
        const unsigned short* gx = an + (grp + t) * 8;   // per-lane source
        char* dx = (char*)Xl + (kk2 * 128 + dm * 64) * 16;
        __builtin_amdgcn_global_load_lds((const __attribute__((address_space(1))) void*)gx,
                                         (__attribute__((address_space(3))) void*)dx, 16, 0, 0);
      }
    #pragma unroll
    for (int r = 0; r < 8; ++r) {
      const int flat = r * 64 + t;
      const int ckk = flat >> 8, crow = (flat >> 2) & 63, chi = flat & 3;
      const unsigned short* gc = cb + (size_t)crow * K_DIM + kt * 64 + ckk * 32 + chi * 8;
      char* dc = (char*)Cl + r * 1024;
      __builtin_amdgcn_global_load_lds((const __attribute__((address_space(1))) void*)gc,
                                       (__attribute__((address_space(3))) void*)dc, 16, 0, 0);
    }
    __syncthreads();

    #pragma unroll
    for (int kk = 0; kk < 2; ++kk) {
      bf16x8 af[2], cf[4];
      #pragma unroll
      for (int dm = 0; dm < 2; ++dm)
        af[dm] = *(const bf16x8*)&Xl[kk * 1024 + dm * 512 + t * 8];
      #pragma unroll
      for (int ni = 0; ni < 4; ++ni)
        cf[ni] = *(const bf16x8*)&Cl[kk * 2048 + (ni * 16 + lr) * 32 + hi4 * 8];
      #pragma unroll
      for (int dm = 0; dm < 2; ++dm)
        #pragma unroll
        for (int ni = 0; ni < 4; ++ni)
          acc[dm][ni] = __builtin_amdgcn_mfma_f32_16x16x32_bf16(af[dm], cf[ni], acc[dm][ni], 0, 0, 0);
    }
    __syncthreads();
  }

  bool colflag[4] = {false, false, false, false};
  #pragma unroll
  for (int dm = 0; dm < 2; ++dm) {
    #pragma unroll
    for (int j = 0; j < 4; ++j) {
      const float v0 = acc[dm][0][j], v1 = acc[dm][1][j],
                  v2 = acc[dm][2][j], v3 = acc[dm][3][j];
      float m = fmaxf(fmaxf(v0, v1), fmaxf(v2, v3));
      #pragma unroll
      for (int off = 8; off >= 1; off >>= 1) m = fmaxf(m, __shfl_xor(m, off));
      float S = expf(v0 - m) + expf(v1 - m) + expf(v2 - m) + expf(v3 - m);
      #pragma unroll
      for (int off = 8; off >= 1; off >>= 1) S += __shfl_xor(S, off);
      const float thr = logf(1e-4f * S);
      colflag[0] |= (v0 - m) > thr;
      colflag[1] |= (v1 - m) > thr;
      colflag[2] |= (v2 - m) > thr;
      colflag[3] |= (v3 - m) > thr;
    }
  }
  unsigned long long bits = 0;
  #pragma unroll
  for (int ni = 0; ni < 4; ++ni) {
    unsigned long long u = __ballot(colflag[ni]);
    u |= u >> 32; u |= u >> 16;
    bits |= (u & 0xFFFFull) << (ni * 16);
  }
  if (t == 0) atomicOr(mask, bits);
}

// ---------------- hybrid bf16 MFMA GEMM: A via LDS (1x), B direct (2x) ----------------
// Block 256x256, 8 waves (2 wm x 4 wn), wave tile 128x64, acc[8][4] (128 AGPR).
// Register diet vs R10: single Af[8] (32 VGPR) reloaded per kk-half; kk0's
// MFMA block covers kk1's ds_reads. ~210 regs total < 256 cap at (512,2).
// Queue discipline per kt: issue B1(kt), S(kt+1), B0(kt+1); auto-waits drain
// only the consumed batch (vmcnt 8); end WAITV(4) drains S, leaves B0 flying.
__global__ __launch_bounds__(512, 2) void gemm_kernel(
    const unsigned short* __restrict__ an, const unsigned short* __restrict__ bnat,
    const float* __restrict__ bias, const int* __restrict__ assign,
    const unsigned long long* __restrict__ maskp,
    float* __restrict__ out) {
  __shared__ unsigned short Al[2][16384];   // 2 x 32 KB

  const int t = threadIdx.x;
  const int l = t & 63;
  const int w = t >> 6;          // 0..7
  const int wm = w & 1;
  const int wn = w >> 1;         // 0..3
  const int lr = l & 15;
  const int hi4 = l >> 4;

  const int bid = blockIdx.x;
  const int swz = (bid & 7) * (gridDim.x >> 3) + (bid >> 3);   // 512 % 8 == 0
  const int bm = swz >> 4, bn = swz & 15;                      // 32 x 16 tiles
  const int m0 = bm * 256, n0 = bn * 256;

  const unsigned short* pB = bnat + ((size_t)bn * 32768 + wn * 64 + l) * 8;
  const size_t aBase = (size_t)bm * 32768;   // group units

  f32x4 acc[8][4];
  #pragma unroll
  for (int i = 0; i < 8; ++i)
    #pragma unroll
    for (int j = 0; j < 4; ++j) acc[i][j] = {0.f, 0.f, 0.f, 0.f};

  bf16x8 Af[8];      // single kk-half of A fragments (32 VGPR)
  bf16x8 Bf[2][4];   // [kk-slot][ni] (32 VGPR)

#define ASTAGE(KT) do {                                                        \
    _Pragma("unroll")                                                          \
    for (int _r = 0; _r < 4; ++_r) {                                           \
      const unsigned short* _g = an + (aBase + (size_t)(KT) * 2048 + _r * 512 + t) * 8; \
      char* _d = (char*)&Al[0][0] + (((KT) & 1) << 15) + (_r * 512 + w * 64) * 16; \
      __builtin_amdgcn_global_load_lds(                                        \
          (const __attribute__((address_space(1))) void*)_g,                   \
          (__attribute__((address_space(3))) void*)_d, 16, 0, 0);              \
    }                                                                          \
  } while (0)

#define LDAF(KT, KK) do {                                                      \
    _Pragma("unroll")                                                          \
    for (int _mi = 0; _mi < 8; ++_mi)                                          \
      Af[_mi] = *(const bf16x8*)((char*)&Al[0][0] + (((KT) & 1) << 15)         \
                 + (KK) * 16384 + _mi * 2048 + (wm * 64 + l) * 16);            \
  } while (0)

#define LDBF(SLOT, KT, KK) do {                                                \
    _Pragma("unroll")                                                          \
    for (int _ni = 0; _ni < 4; ++_ni)                                          \
      Bf[SLOT][_ni] = *(const bf16x8*)(pB + ((size_t)(KT) * 2048 + (KK) * 1024 + _ni * 256) * 8); \
  } while (0)

#define MFMAS(SLOT) do {                                                       \
    __builtin_amdgcn_s_setprio(1);                                             \
    _Pragma("unroll")                                                          \
    for (int _mi = 0; _mi < 8; ++_mi)                                          \
      _Pragma("unroll")                                                        \
      for (int _ni = 0; _ni < 4; ++_ni)                                        \
        acc[_mi][_ni] = __builtin_amdgcn_mfma_f32_16x16x32_bf16(               \
            Af[_mi], Bf[SLOT][_ni], acc[_mi][_ni], 0, 0, 0);                   \
    __builtin_amdgcn_s_setprio(0);                                             \
  } while (0)

#define WAITV(N) asm volatile("s_waitcnt vmcnt(" #N ")" ::: "memory")
#define BAR() do { asm volatile("" ::: "memory"); __builtin_amdgcn_s_barrier(); } while (0)

  // ---- prologue: stage A(0), prefetch B0(0) ----
  ASTAGE(0);
  LDBF(0, 0, 0);
  WAITV(4);            // drain A-stage (own share); B0(0) stays in flight
  BAR();

  // ---- main loop: kt = 0..14 ----
  for (int kt = 0; kt < 15; ++kt) {
    LDAF(kt, 0);       // 8 ds_reads (kk0 frags)
    LDBF(1, kt, 1);    // issue B1(kt)
    ASTAGE(kt + 1);    // issue S(kt+1) into buf^1
    MFMAS(0);          // auto-wait drains B0(kt) only (vmcnt 8); lgkm for Af
    LDAF(kt, 1);       // reload Af with kk1 frags (covered by MFMAS(0))
    LDBF(0, kt + 1, 0);// issue B0(kt+1)
    MFMAS(1);          // auto-wait drains B1(kt) only (vmcnt 8)
    WAITV(4);          // drain S(kt+1); B0(kt+1) stays in flight
    BAR();
  }

  // ---- tail: kt = 15 ----
  LDAF(15, 0);
  LDBF(1, 15, 1);
  MFMAS(0);
  LDAF(15, 1);
  MFMAS(1);

  // ---- epilogue: fused mask + bias ----
  const unsigned long long mask = *maskp;
  #pragma unroll
  for (int ni = 0; ni < 4; ++ni) {
    const int col = n0 + wn * 64 + ni * 16 + lr;
    const int a = assign[col];
    const bool act = (mask >> a) & 1ull;
    const float bv = bias[col];
    #pragma unroll
    for (int mi = 0; mi < 8; ++mi) {
      const int rowb = m0 + wm * 128 + mi * 16 + hi4 * 4;
      #pragma unroll
      for (int j = 0; j < 4; ++j) {
        out[(size_t)(rowb + j) * N_COLS + col] = act ? (acc[mi][ni][j] + bv) : 0.0f;
      }
    }
  }
#undef ASTAGE
#undef LDAF
#undef LDBF
#undef MFMAS
#undef WAITV
#undef BAR
}

extern "C" void kernel_launch(void* const* d_in, const int* in_sizes, int n_in,
                              void* d_out, int out_size, void* d_ws, size_t ws_size,
                              hipStream_t stream) {
  const float* x    = (const float*)d_in[0];
  const float* wgt  = (const float*)d_in[1];
  const float* bias = (const float*)d_in[2];
  const float* cent = (const float*)d_in[3];
  const int* assign = (const int*)d_in[4];
  float* out = (float*)d_out;

  unsigned long long* mask = (unsigned long long*)d_ws;
  unsigned short* an   = (unsigned short*)((char*)d_ws + 256);
  unsigned short* bnat = an + (size_t)A_GROUPS * 8;    // +16 MB
  unsigned short* cb   = bnat + (size_t)B_GROUPS * 8;  // +8 MB (cb: 128 KB)

  const unsigned total_groups = A_GROUPS + B_GROUPS + C_GROUPS;
  hipLaunchKernelGGL(convert_kernel, dim3(total_groups / 256), dim3(256), 0, stream,
                     x, wgt, cent, an, bnat, cb, mask);
  hipLaunchKernelGGL(routing_mfma_kernel, dim3(256), dim3(64), 0, stream,
                     an, cb, mask);
  hipLaunchKernelGGL(gemm_kernel, dim3((M_ROWS / 256) * (N_COLS / 256)), dim3(512), 0, stream,
                     an, bnat, bias, assign, mask, out);
}

// Round 12
// 106.111 us; speedup vs baseline: 18.0400x; 1.0324x over previous
//
#include <hip/hip_runtime.h>
#include <hip/hip_bf16.h>
#include <stdint.h>

#define M_ROWS 8192
#define K_DIM  1024
#define N_COLS 4096
#define N_CLUS 64

// fragment-native layout (16B groups of 8 bf16):
// A: [bm(32)][kt(16)][kk(2)][mi(8)][wm(2)][l(64)]   -> 32768 groups / bm
//    (equivalently 64 panels of 128 rows: bmp=(bm,wm))
// B: [bn(16)][kt(16)][kk(2)][ni(4)][wn(4)][l(64)]   -> 32768 groups / bn
// group (.,l) holds src[row][k0..k0+8): row = base + frag*16 + (l&15),
// k0 = kt*64 + (kk*4 + (l>>4))*8.
#define A_GROUPS (32u * 32768u)   // 1048576
#define B_GROUPS (16u * 32768u)   // 524288
#define C_GROUPS (64u * 128u)     // 8192

typedef short bf16x8 __attribute__((ext_vector_type(8)));
typedef float f32x4  __attribute__((ext_vector_type(4)));

__device__ __forceinline__ unsigned short f2bf(float f) {
  unsigned int u = __float_as_uint(f);
  unsigned int r = (u + 0x7FFFu + ((u >> 16) & 1u)) >> 16;
  return (unsigned short)r;
}

// ---------------- fp32 -> bf16 native-layout conversion + mask init ----------------
__global__ __launch_bounds__(256) void convert_kernel(
    const float* __restrict__ x, const float* __restrict__ wgt,
    const float* __restrict__ cent,
    unsigned short* __restrict__ an, unsigned short* __restrict__ bnat,
    unsigned short* __restrict__ cb,
    unsigned long long* __restrict__ mask) {
  const unsigned g = blockIdx.x * 256 + threadIdx.x;
  if (g == 0) *mask = 0ull;
  const float* src; unsigned short* dst; unsigned row, k0;
  if (g < A_GROUPS) {
    const unsigned o = g;
    const unsigned l = o & 63, wm = (o >> 6) & 1, mi = (o >> 7) & 7,
                   kk = (o >> 10) & 1, kt = (o >> 11) & 15, bm = o >> 15;
    row = bm * 256 + wm * 128 + mi * 16 + (l & 15);
    k0  = kt * 64 + (kk * 4 + (l >> 4)) * 8;
    src = x; dst = an + (size_t)o * 8;
  } else if (g < A_GROUPS + B_GROUPS) {
    const unsigned o = g - A_GROUPS;
    const unsigned l = o & 63, wn = (o >> 6) & 3, ni = (o >> 8) & 3,
                   kk = (o >> 10) & 1, kt = (o >> 11) & 15, bn = o >> 15;
    row = bn * 256 + wn * 64 + ni * 16 + (l & 15);
    k0  = kt * 64 + (kk * 4 + (l >> 4)) * 8;
    src = wgt; dst = bnat + (size_t)o * 8;
  } else {
    const unsigned o = g - A_GROUPS - B_GROUPS;
    row = o >> 7; k0 = (o & 127) * 8;
    src = cent; dst = cb + (size_t)o * 8;
  }
  const float4 v0 = *(const float4*)&src[(size_t)row * K_DIM + k0];
  const float4 v1 = *(const float4*)&src[(size_t)row * K_DIM + k0 + 4];
  union { unsigned short u[8]; uint4 q; } o16;
  o16.u[0] = f2bf(v0.x); o16.u[1] = f2bf(v0.y); o16.u[2] = f2bf(v0.z); o16.u[3] = f2bf(v0.w);
  o16.u[4] = f2bf(v1.x); o16.u[5] = f2bf(v1.y); o16.u[6] = f2bf(v1.z); o16.u[7] = f2bf(v1.w);
  *(uint4*)dst = o16.q;
}

// ---------------- routing (reads native A layout): cluster-active mask ----------------
// 256 blocks x 1 wave; block = (bm, wm, mp) -> rows bm*256+wm*128+mp*32 .. +32.
__global__ __launch_bounds__(64) void routing_mfma_kernel(
    const unsigned short* __restrict__ an, const unsigned short* __restrict__ cb,
    unsigned long long* __restrict__ mask) {
  __shared__ unsigned short Xl[2048];   // 4 KB: groups [kk][dm][l]
  __shared__ unsigned short Cl[4096];   // 8 KB: groups [kk][crow][chi]
  const int t = threadIdx.x;
  const int lr = t & 15;
  const int hi4 = t >> 4;
  const int bm = blockIdx.x >> 3, wm = (blockIdx.x >> 2) & 1, mp = blockIdx.x & 3;
  const size_t abase = (size_t)bm * 32768 + wm * 64;   // group units

  f32x4 acc[2][4];
  #pragma unroll
  for (int i = 0; i < 2; ++i)
    #pragma unroll
    for (int j = 0; j < 4; ++j) acc[i][j] = {0.f, 0.f, 0.f, 0.f};

  for (int kt = 0; kt < 16; ++kt) {
    #pragma unroll
    for (int kk2 = 0; kk2 < 2; ++kk2)
      #pragma unroll
      for (int dm = 0; dm < 2; ++dm) {
        const size_t grp = abase + kt * 2048 + kk2 * 1024 + (mp * 2 + dm) * 128;
        const unsigned short* gx = an + (grp + t) * 8;   // per-lane source
        char* dx = (char*)Xl + (kk2 * 128 + dm * 64) * 16;
        __builtin_amdgcn_global_load_lds((const __attribute__((address_space(1))) void*)gx,
                                         (__attribute__((address_space(3))) void*)dx, 16, 0, 0);
      }
    #pragma unroll
    for (int r = 0; r < 8; ++r) {
      const int flat = r * 64 + t;
      const int ckk = flat >> 8, crow = (flat >> 2) & 63, chi = flat & 3;
      const unsigned short* gc = cb + (size_t)crow * K_DIM + kt * 64 + ckk * 32 + chi * 8;
      char* dc = (char*)Cl + r * 1024;
      __builtin_amdgcn_global_load_lds((const __attribute__((address_space(1))) void*)gc,
                                       (__attribute__((address_space(3))) void*)dc, 16, 0, 0);
    }
    __syncthreads();

    #pragma unroll
    for (int kk = 0; kk < 2; ++kk) {
      bf16x8 af[2], cf[4];
      #pragma unroll
      for (int dm = 0; dm < 2; ++dm)
        af[dm] = *(const bf16x8*)&Xl[kk * 1024 + dm * 512 + t * 8];
      #pragma unroll
      for (int ni = 0; ni < 4; ++ni)
        cf[ni] = *(const bf16x8*)&Cl[kk * 2048 + (ni * 16 + lr) * 32 + hi4 * 8];
      #pragma unroll
      for (int dm = 0; dm < 2; ++dm)
        #pragma unroll
        for (int ni = 0; ni < 4; ++ni)
          acc[dm][ni] = __builtin_amdgcn_mfma_f32_16x16x32_bf16(af[dm], cf[ni], acc[dm][ni], 0, 0, 0);
    }
    __syncthreads();
  }

  bool colflag[4] = {false, false, false, false};
  #pragma unroll
  for (int dm = 0; dm < 2; ++dm) {
    #pragma unroll
    for (int j = 0; j < 4; ++j) {
      const float v0 = acc[dm][0][j], v1 = acc[dm][1][j],
                  v2 = acc[dm][2][j], v3 = acc[dm][3][j];
      float m = fmaxf(fmaxf(v0, v1), fmaxf(v2, v3));
      #pragma unroll
      for (int off = 8; off >= 1; off >>= 1) m = fmaxf(m, __shfl_xor(m, off));
      float S = expf(v0 - m) + expf(v1 - m) + expf(v2 - m) + expf(v3 - m);
      #pragma unroll
      for (int off = 8; off >= 1; off >>= 1) S += __shfl_xor(S, off);
      const float thr = logf(1e-4f * S);
      colflag[0] |= (v0 - m) > thr;
      colflag[1] |= (v1 - m) > thr;
      colflag[2] |= (v2 - m) > thr;
      colflag[3] |= (v3 - m) > thr;
    }
  }
  unsigned long long bits = 0;
  #pragma unroll
  for (int ni = 0; ni < 4; ++ni) {
    unsigned long long u = __ballot(colflag[ni]);
    u |= u >> 32; u |= u >> 16;
    bits |= (u & 0xFFFFull) << (ni * 16);
  }
  if (t == 0) atomicOr(mask, bits);
}

// ---------------- LDS-free bf16 MFMA GEMM: 4-wave blocks, 2 blocks/CU ----------------
// Block 128x256 (4 waves = wn, wave tile 128x64), grid 1024 (4 rounds/CU, 2
// resident). Same per-wave profile as the proven R7 kernel (12 frags/32 MFMAs,
// 2-slot pipeline, ~256 unified regs) — but two independent blocks per CU give
// cross-block latency hiding in the K-loop and stagger the epilogue writes so
// the 21 us HBM write floor overlaps compute instead of serializing.
__global__ __launch_bounds__(256, 2) void gemm_kernel(
    const unsigned short* __restrict__ an, const unsigned short* __restrict__ bnat,
    const float* __restrict__ bias, const int* __restrict__ assign,
    const unsigned long long* __restrict__ maskp,
    float* __restrict__ out) {
  const int t = threadIdx.x;
  const int l = t & 63;
  const int w = t >> 6;          // 0..3 = wn
  const int lr = l & 15;
  const int hi4 = l >> 4;

  const int bid = blockIdx.x;
  const int swz = (bid & 7) * (gridDim.x >> 3) + (bid >> 3);   // 1024 % 8 == 0
  // balanced XCD mapping: each XCD chunk of 128 swz -> 16 bmp x 8 bn
  const int xc = swz >> 7, xi = swz & 127;
  const int bmp = (xc & 3) * 16 + (xi >> 3);   // 0..63 (128-row panel)
  const int bn  = (xc >> 2) * 8 + (xi & 7);    // 0..15 (256-col panel)
  const int m0 = bmp * 128, n0 = bn * 256;

  const unsigned short* pA = an   + ((size_t)(bmp >> 1) * 32768 + (bmp & 1) * 64 + l) * 8;
  const unsigned short* pB = bnat + ((size_t)bn * 32768 + w * 64 + l) * 8;

  f32x4 acc[8][4];
  #pragma unroll
  for (int i = 0; i < 8; ++i)
    #pragma unroll
    for (int j = 0; j < 4; ++j) acc[i][j] = {0.f, 0.f, 0.f, 0.f};

  struct Frags { bf16x8 a[8]; bf16x8 b[4]; };
  Frags P0, P1;

#define LOADP(P, S) do {                                                       \
    _Pragma("unroll")                                                          \
    for (int _mi = 0; _mi < 8; ++_mi)                                          \
      P.a[_mi] = *(const bf16x8*)(pA + ((S) * 1024 + _mi * 128) * 8);          \
    _Pragma("unroll")                                                          \
    for (int _ni = 0; _ni < 4; ++_ni)                                          \
      P.b[_ni] = *(const bf16x8*)(pB + ((S) * 1024 + _ni * 256) * 8);          \
  } while (0)

#define MFMAP(P) do {                                                          \
    __builtin_amdgcn_s_setprio(1);                                             \
    _Pragma("unroll")                                                          \
    for (int _mi = 0; _mi < 8; ++_mi)                                          \
      _Pragma("unroll")                                                        \
      for (int _ni = 0; _ni < 4; ++_ni)                                        \
        acc[_mi][_ni] = __builtin_amdgcn_mfma_f32_16x16x32_bf16(               \
            P.a[_mi], P.b[_ni], acc[_mi][_ni], 0, 0, 0);                       \
    __builtin_amdgcn_s_setprio(0);                                             \
  } while (0)

  LOADP(P0, 0);
  for (int s = 0; s < 30; s += 2) {
    LOADP(P1, s + 1);
    MFMAP(P0);
    LOADP(P0, s + 2);
    MFMAP(P1);
  }
  LOADP(P1, 31);
  MFMAP(P0);
  MFMAP(P1);

  // ---- epilogue: fused mask + bias ----
  const unsigned long long mask = *maskp;
  #pragma unroll
  for (int ni = 0; ni < 4; ++ni) {
    const int col = n0 + w * 64 + ni * 16 + lr;
    const int a = assign[col];
    const bool act = (mask >> a) & 1ull;
    const float bv = bias[col];
    #pragma unroll
    for (int mi = 0; mi < 8; ++mi) {
      const int rowb = m0 + mi * 16 + hi4 * 4;
      #pragma unroll
      for (int j = 0; j < 4; ++j) {
        out[(size_t)(rowb + j) * N_COLS + col] = act ? (acc[mi][ni][j] + bv) : 0.0f;
      }
    }
  }
#undef LOADP
#undef MFMAP
}

extern "C" void kernel_launch(void* const* d_in, const int* in_sizes, int n_in,
                              void* d_out, int out_size, void* d_ws, size_t ws_size,
                              hipStream_t stream) {
  const float* x    = (const float*)d_in[0];
  const float* wgt  = (const float*)d_in[1];
  const float* bias = (const float*)d_in[2];
  const float* cent = (const float*)d_in[3];
  const int* assign = (const int*)d_in[4];
  float* out = (float*)d_out;

  unsigned long long* mask = (unsigned long long*)d_ws;
  unsigned short* an   = (unsigned short*)((char*)d_ws + 256);
  unsigned short* bnat = an + (size_t)A_GROUPS * 8;    // +16 MB
  unsigned short* cb   = bnat + (size_t)B_GROUPS * 8;  // +8 MB (cb: 128 KB)

  const unsigned total_groups = A_GROUPS + B_GROUPS + C_GROUPS;
  hipLaunchKernelGGL(convert_kernel, dim3(total_groups / 256), dim3(256), 0, stream,
                     x, wgt, cent, an, bnat, cb, mask);
  hipLaunchKernelGGL(routing_mfma_kernel, dim3(256), dim3(64), 0, stream,
                     an, cb, mask);
  hipLaunchKernelGGL(gemm_kernel, dim3((M_ROWS / 128) * (N_COLS / 256)), dim3(256), 0, stream,
                     an, bnat, bias, assign, mask, out);
}